// Round 4
// baseline (489.483 us; speedup 1.0000x reference)
//
#include <hip/hip_runtime.h>
#include <hip/hip_cooperative_groups.h>

namespace cg = cooperative_groups;

#define EPS 1e-5f
constexpr float INV_N1 = 1.f / 524288.f;   // D*U*2
constexpr float INV_N3 = 1.f / 262144.f;   // D*U

__device__ __forceinline__ float lrelu(float y) { return fmaxf(y, 0.01f * y); }

// ---- DPP reduction helpers (VALU pipe, no LDS/bpermute) -------------------
template <int CTRL>
__device__ __forceinline__ float dppMov(float v) {
    return __int_as_float(__builtin_amdgcn_update_dpp(
        0, __float_as_int(v), CTRL, 0xF, 0xF, true));
}
// full 64-lane sum, valid in lane 63
__device__ __forceinline__ float waveSumDpp(float v) {
    v += dppMov<0x111>(v);  // row_shr:1
    v += dppMov<0x112>(v);  // row_shr:2
    v += dppMov<0x114>(v);  // row_shr:4
    v += dppMov<0x118>(v);  // row_shr:8
    v += dppMov<0x142>(v);  // row_bcast:15
    v += dppMov<0x143>(v);  // row_bcast:31
    return v;
}
// sum within each 16-lane row, valid in lane row*16+15
__device__ __forceinline__ float rowSumDpp(float v) {
    v += dppMov<0x111>(v);
    v += dppMov<0x112>(v);
    v += dppMov<0x114>(v);
    v += dppMov<0x118>(v);
    return v;
}
__device__ __forceinline__ float waveAllSum(float v) {
    v += __shfl_xor(v, 32); v += __shfl_xor(v, 16); v += __shfl_xor(v, 8);
    v += __shfl_xor(v, 4);  v += __shfl_xor(v, 2);  v += __shfl_xor(v, 1);
    return v;
}

struct KArgs {
    const float *x, *w1, *b1, *w21, *w22, *b21, *b22, *w3, *b3, *bias;
    const float *g0, *be0, *g1, *be1, *g2, *be2, *g3, *be3;
    float *out;
    float *xn, *S1, *S2, *S11, *S0b, *Sb2, *rs1a, *mm1a, *Xs;
    float *G3s, *Be3s, *st2, *Gp, *Bp, *qp, *pp;
};

struct SmP2 { float xcol[64], scA[64], scB[64]; float red[64][4][2]; };           // 2816 B
struct SmP3 { float4 sc[64]; float sxn[64][16]; float qacc[4][64][2]; };          // 7168 B

__global__ void __launch_bounds__(256, 4) fused(KArgs a) {
    cg::grid_group grid = cg::this_grid();
    const int bid = blockIdx.x, tid = threadIdx.x;
    const int wave = tid >> 6, lane = tid & 63;
    __shared__ __align__(16) char smraw[sizeof(SmP3)];
    __shared__ float redA[4][8];
    __shared__ float bcS[4];
    SmP2& m2s = *reinterpret_cast<SmP2*>(smraw);
    SmP3& m3s = *reinterpret_cast<SmP3*>(smraw);

    // ============ P0: weight sums, g3/be3 partials, LN0->xn, zero st2 ======
    if (bid < 512) {
        const float4* wr = (const float4*)(a.w1 + bid * 1024);
        const float4* br = (const float4*)(a.b1 + bid * 1024);
        float4 w = wr[tid], b = br[tid];
        float s1  = w.x + w.y + w.z + w.w;
        float s2  = w.x * w.x + w.y * w.y + w.z * w.z + w.w * w.w;
        float s11 = w.x * b.x + w.y * b.y + w.z * b.z + w.w * b.w;
        float s0  = b.x + b.y + b.z + b.w;
        float sb2 = b.x * b.x + b.y * b.y + b.z * b.z + b.w * b.w;
        s1 = waveAllSum(s1); s2 = waveAllSum(s2); s11 = waveAllSum(s11);
        s0 = waveAllSum(s0); sb2 = waveAllSum(sb2);
        if (lane == 0) {
            redA[wave][0] = s1; redA[wave][1] = s2; redA[wave][2] = s11;
            redA[wave][3] = s0; redA[wave][4] = sb2;
        }
        __syncthreads();
        if (tid == 0) {
            float a0 = 0, a1 = 0, a2 = 0, a3 = 0, a4 = 0;
            for (int w4 = 0; w4 < 4; ++w4) {
                a0 += redA[w4][0]; a1 += redA[w4][1]; a2 += redA[w4][2];
                a3 += redA[w4][3]; a4 += redA[w4][4];
            }
            a.S1[bid] = a0; a.S2[bid] = a1; a.S11[bid] = a2;
            a.S0b[bid] = a3; a.Sb2[bid] = a4;
        }
    } else if (bid < 576) {
        int jj = bid - 512;   // 8 d-rows each, plain partial stores
        float ag0 = 0, ag1 = 0, ab0 = 0, ab1 = 0;
#pragma unroll
        for (int r = 0; r < 8; ++r) {
            const float* gr = a.g3 + (jj * 8 + r) * 512;
            const float* br = a.be3 + (jj * 8 + r) * 512;
            ag0 += gr[tid]; ag1 += gr[tid + 256];
            ab0 += br[tid]; ab1 += br[tid + 256];
        }
        a.Gp[jj * 512 + tid] = ag0; a.Gp[jj * 512 + tid + 256] = ag1;
        a.Bp[jj * 512 + tid] = ab0; a.Bp[jj * 512 + tid + 256] = ab1;
    } else if (bid < 640) {
        int b = bid - 576;
        float2 xv = ((const float2*)(a.x + b * 512))[tid];
        float sx = xv.x + xv.y, sxx = xv.x * xv.x + xv.y * xv.y;
        sx = waveAllSum(sx); sxx = waveAllSum(sxx);
        if (lane == 0) { redA[wave][0] = sx; redA[wave][1] = sxx; }
        __syncthreads();
        if (tid == 0) {
            float s = redA[0][0] + redA[1][0] + redA[2][0] + redA[3][0];
            float c = redA[0][1] + redA[1][1] + redA[2][1] + redA[3][1];
            float m = s * (1.f / 512.f);
            float var = c * (1.f / 512.f) - m * m;
            bcS[0] = m; bcS[1] = rsqrtf(var + EPS);
        }
        __syncthreads();
        float m = bcS[0], rsd = bcS[1];
        float2 g = ((const float2*)a.g0)[tid], be = ((const float2*)a.be0)[tid];
        float xn0 = (xv.x - m) * rsd * g.x + be.x;
        float xn1 = (xv.y - m) * rsd * g.y + be.y;
        ((float2*)(a.xn + b * 512))[tid] = make_float2(xn0, xn1);
        float sxn = waveAllSum(xn0 + xn1);
        __syncthreads();
        if (lane == 0) redA[wave][0] = sxn;
        __syncthreads();
        if (tid == 0) a.Xs[b] = redA[0][0] + redA[1][0] + redA[2][0] + redA[3][0];
    } else if (bid == 640) {
        for (int t = tid; t < 2048; t += 256) a.st2[t] = 0.f;   // padded accum
    }
    grid.sync();

    // ============ P1: LN1 stats per batch; fold G3s/Be3s ===================
    if (bid < 64) {
        int b = bid;
        float2 xv  = ((const float2*)(a.xn + b * 512))[tid];
        float2 s1  = ((const float2*)a.S1)[tid],  s0b = ((const float2*)a.S0b)[tid];
        float2 s2  = ((const float2*)a.S2)[tid],  s11 = ((const float2*)a.S11)[tid];
        float2 sb2 = ((const float2*)a.Sb2)[tid];
        float pm = fmaf(xv.x, s1.x, s0b.x) + fmaf(xv.y, s1.y, s0b.y);
        float pe = xv.x * xv.x * s2.x + 2.f * xv.x * s11.x + sb2.x
                 + xv.y * xv.y * s2.y + 2.f * xv.y * s11.y + sb2.y;
        pm = waveAllSum(pm); pe = waveAllSum(pe);
        if (lane == 0) { redA[wave][0] = pm; redA[wave][1] = pe; }
        __syncthreads();
        if (tid == 0) {
            float s = redA[0][0] + redA[1][0] + redA[2][0] + redA[3][0];
            float c = redA[0][1] + redA[1][1] + redA[2][1] + redA[3][1];
            float m1 = s * INV_N1, e1 = c * INV_N1;
            float r = rsqrtf(e1 - m1 * m1 + EPS);
            a.rs1a[b] = r; a.mm1a[b] = m1 * r;
        }
    } else if (bid == 64) {
        for (int u = tid; u < 512; u += 256) {
            float s = 0;
#pragma unroll 8
            for (int jj = 0; jj < 64; ++jj) s += a.Gp[jj * 512 + u];
            a.G3s[u] = s;
        }
    } else if (bid == 65) {
        for (int u = tid; u < 512; u += 256) {
            float s = 0;
#pragma unroll 8
            for (int jj = 0; jj < 64; ++jj) s += a.Bp[jj * 512 + u];
            a.Be3s[u] = s;
        }
    }
    grid.sync();

    // ============ P2: LN2 stat partials (all 1024 blocks) ==================
    {
        int d = bid >> 1;
        int u = ((bid & 1) << 8) + tid;
        int i = d * 512 + u;
        float2 W1 = ((const float2*)a.w1)[i], B1 = ((const float2*)a.b1)[i];
        float2 G1 = ((const float2*)a.g1)[i], E1 = ((const float2*)a.be1)[i];
        float2 A  = ((const float2*)a.w21)[i], C = ((const float2*)a.w22)[i];
        float Ba = a.b21[i], Bc = a.b22[i];
        if (tid < 64) {
            m2s.xcol[tid] = a.xn[tid * 512 + d];
            m2s.scA[tid] = a.rs1a[tid];
            m2s.scB[tid] = a.mm1a[tid];
        }
        __syncthreads();
        for (int b = 0; b < 64; ++b) {
            float rs1 = m2s.scA[b], mm1 = m2s.scB[b], xd = m2s.xcol[b];
            float t0 = fmaf(xd, W1.x, B1.x), t1 = fmaf(xd, W1.y, B1.y);
            float z0 = fmaf(t0, rs1, -mm1), z1 = fmaf(t1, rs1, -mm1);
            float y0 = fmaf(z0, G1.x, E1.x), y1 = fmaf(z1, G1.y, E1.y);
            float l0 = lrelu(y0), l1 = lrelu(y1);
            float c0 = fmaf(l0, A.x, fmaf(l1, A.y, Ba));
            float c1 = fmaf(l0, C.x, fmaf(l1, C.y, Bc));
            float v1 = c0 + c1;
            float v2 = fmaf(c0, c0, c1 * c1);
            v1 = waveSumDpp(v1); v2 = waveSumDpp(v2);
            if (lane == 63) { m2s.red[b][wave][0] = v1; m2s.red[b][wave][1] = v2; }
        }
        __syncthreads();
        if (tid < 128) {     // tid = b*2+k; one padded f32 atomic per line
            int b = tid >> 1, k = tid & 1;
            float s = m2s.red[b][0][k] + m2s.red[b][1][k]
                    + m2s.red[b][2][k] + m2s.red[b][3][k];
            unsafeAtomicAdd(&a.st2[tid * 16], s);
        }
    }
    grid.sync();

    // ============ P3: main fused pass (all 1024 blocks) ====================
    {
        int bd = bid >> 5, bu = bid & 31;
        int dloc = lane & 15, uloc = wave * 4 + (lane >> 4);
        int d = bd * 16 + dloc, u = bu * 16 + uloc;
        int i = d * 512 + u;
        float2 W1 = ((const float2*)a.w1)[i], B1 = ((const float2*)a.b1)[i];
        float2 G1 = ((const float2*)a.g1)[i], E1 = ((const float2*)a.be1)[i];
        float2 A  = ((const float2*)a.w21)[i], C = ((const float2*)a.w22)[i];
        float2 G2 = ((const float2*)a.g2)[i], E2 = ((const float2*)a.be2)[i];
        float2 W3 = ((const float2*)a.w3)[i];
        float Ba = a.b21[i], Bc = a.b22[i], B3 = a.b3[i], G3v = a.g3[i];
        if (tid < 64) {
            float ssum = a.st2[(tid * 2) * 16], s2sum = a.st2[(tid * 2 + 1) * 16];
            float mm = ssum * INV_N1;
            float var = s2sum * INV_N1 - mm * mm;
            float r2 = rsqrtf(var + EPS);
            m3s.sc[tid] = make_float4(a.rs1a[tid], a.mm1a[tid], r2, mm * r2);
        }
        for (int idx = tid; idx < 1024; idx += 256)
            m3s.sxn[idx >> 4][idx & 15] = a.xn[(idx >> 4) * 512 + bd * 16 + (idx & 15)];
        __syncthreads();
        for (int b = 0; b < 64; ++b) {
            float4 s4 = m3s.sc[b];   // rs1, m1*rs1, rs2, m2*rs2
            float xd = m3s.sxn[b][dloc];
            float t0 = fmaf(xd, W1.x, B1.x), t1 = fmaf(xd, W1.y, B1.y);
            float z0 = fmaf(t0, s4.x, -s4.y), z1 = fmaf(t1, s4.x, -s4.y);
            float y0 = fmaf(z0, G1.x, E1.x), y1 = fmaf(z1, G1.y, E1.y);
            float l0 = lrelu(y0), l1 = lrelu(y1);
            float c0 = fmaf(l0, A.x, fmaf(l1, A.y, Ba));
            float c1 = fmaf(l0, C.x, fmaf(l1, C.y, Bc));
            float z20 = fmaf(c0, s4.z, -s4.w), z21 = fmaf(c1, s4.z, -s4.w);
            float y20 = fmaf(z20, G2.x, E2.x), y21 = fmaf(z21, G2.y, E2.y);
            float m0 = lrelu(y20), m1v = lrelu(y21);
            float l3 = fmaf(m0, W3.x, fmaf(m1v, W3.y, B3));
            float p = l3 * G3v, q = l3, q2 = l3 * l3;
            p  = rowSumDpp(p);                       // per-u sum over 16 d
            q  = rowSumDpp(q);  q  += dppMov<0x142>(q);  q  += dppMov<0x143>(q);
            q2 = rowSumDpp(q2); q2 += dppMov<0x142>(q2); q2 += dppMov<0x143>(q2);
            if (dloc == 15)
                a.pp[(bd * 64 + b) * 512 + u] = p;   // plain store
            if (lane == 63) { m3s.qacc[wave][b][0] = q; m3s.qacc[wave][b][1] = q2; }
        }
        __syncthreads();
        if (tid < 128) {
            int b = tid >> 1, k = tid & 1;
            float s = m3s.qacc[0][b][k] + m3s.qacc[1][b][k]
                    + m3s.qacc[2][b][k] + m3s.qacc[3][b][k];
            a.qp[(b * 2 + k) * 1024 + bid] = s;      // transposed for P4 reads
        }
    }
    grid.sync();

    // ============ P4: finalize =============================================
    if (bid < 64) {
        int b = bid;
        float qq = 0, qq2 = 0;
        for (int blk = tid; blk < 1024; blk += 256) {
            qq  += a.qp[(b * 2 + 0) * 1024 + blk];
            qq2 += a.qp[(b * 2 + 1) * 1024 + blk];
        }
        qq = waveAllSum(qq); qq2 = waveAllSum(qq2);
        if (lane == 0) { redA[wave][0] = qq; redA[wave][1] = qq2; }
        __syncthreads();
        if (tid == 0) {
            float s = redA[0][0] + redA[1][0] + redA[2][0] + redA[3][0];
            float c = redA[0][1] + redA[1][1] + redA[2][1] + redA[3][1];
            float mn = s * INV_N3, e3 = c * INV_N3;
            bcS[0] = mn; bcS[1] = rsqrtf(e3 - mn * mn + EPS);
        }
        __syncthreads();
        float m3v = bcS[0], rs3 = bcS[1];
        for (int u = tid; u < 512; u += 256) {
            float p = 0;
#pragma unroll 8
            for (int bd = 0; bd < 32; ++bd) p += a.pp[(bd * 64 + b) * 512 + u];
            float val = rs3 * (p - m3v * a.G3s[u]) + a.Be3s[u] + a.Xs[b] + a.bias[u];
            a.out[b * 512 + u] = lrelu(val);
        }
    }
}

extern "C" void kernel_launch(void* const* d_in, const int* in_sizes, int n_in,
                              void* d_out, int out_size, void* d_ws, size_t ws_size,
                              hipStream_t stream) {
    char* ws = (char*)d_ws;
    KArgs ka;
    ka.x   = (const float*)d_in[0];
    ka.w1  = (const float*)d_in[1];
    ka.b1  = (const float*)d_in[2];
    ka.w21 = (const float*)d_in[3];
    ka.w22 = (const float*)d_in[4];
    ka.b21 = (const float*)d_in[5];
    ka.b22 = (const float*)d_in[6];
    ka.w3  = (const float*)d_in[7];
    ka.b3  = (const float*)d_in[8];
    ka.bias= (const float*)d_in[9];
    ka.g0  = (const float*)d_in[10];
    ka.be0 = (const float*)d_in[11];
    ka.g1  = (const float*)d_in[12];
    ka.be1 = (const float*)d_in[13];
    ka.g2  = (const float*)d_in[14];
    ka.be2 = (const float*)d_in[15];
    ka.g3  = (const float*)d_in[16];
    ka.be3 = (const float*)d_in[17];
    ka.out = (float*)d_out;

    ka.xn   = (float*)(ws);               // 131072  [B][D]
    ka.S1   = (float*)(ws + 131072);      // 2048 each
    ka.S2   = (float*)(ws + 133120);
    ka.S11  = (float*)(ws + 135168);
    ka.S0b  = (float*)(ws + 137216);
    ka.Sb2  = (float*)(ws + 139264);
    ka.rs1a = (float*)(ws + 141312);      // 256 each
    ka.mm1a = (float*)(ws + 141568);
    ka.Xs   = (float*)(ws + 141824);
    ka.G3s  = (float*)(ws + 142080);      // 2048
    ka.Be3s = (float*)(ws + 144128);      // 2048
    ka.st2  = (float*)(ws + 146176);      // 8192 (128 entries, 64B stride)
    ka.Gp   = (float*)(ws + 154368);      // 131072 [64][512]
    ka.Bp   = (float*)(ws + 285440);      // 131072
    ka.qp   = (float*)(ws + 416512);      // 524288 [128][1024]
    ka.pp   = (float*)(ws + 940800);      // 4194304 [32][64][512]  (end ~5.1 MB)

    void* kparams[] = { (void*)&ka };
    hipLaunchCooperativeKernel((const void*)fused, dim3(1024), dim3(256),
                               kparams, 0, stream);
}

// Round 5
// 83.286 us; speedup vs baseline: 5.8771x; 5.8771x over previous
//
#include <hip/hip_runtime.h>

#define EPS 1e-5f
constexpr float INV_N1 = 1.f / 524288.f;   // D*U*2
constexpr float INV_N3 = 1.f / 262144.f;   // D*U

__device__ __forceinline__ float lrelu(float y) { return fmaxf(y, 0.01f * y); }

// ---- DPP reduction helpers (VALU pipe) ------------------------------------
template <int CTRL>
__device__ __forceinline__ float dppMov(float v) {
    return __int_as_float(__builtin_amdgcn_update_dpp(
        0, __float_as_int(v), CTRL, 0xF, 0xF, true));
}
// full 64-lane sum, valid in lane 63
__device__ __forceinline__ float waveSumDpp(float v) {
    v += dppMov<0x111>(v);  // row_shr:1
    v += dppMov<0x112>(v);  // row_shr:2
    v += dppMov<0x114>(v);  // row_shr:4
    v += dppMov<0x118>(v);  // row_shr:8
    v += dppMov<0x142>(v);  // row_bcast:15
    v += dppMov<0x143>(v);  // row_bcast:31
    return v;
}
// sum over each 4-lane quad (all quad lanes get it)
__device__ __forceinline__ float quadSum(float v) {
    v += dppMov<0xB1>(v);   // quad_perm xor1
    v += dppMov<0x4E>(v);   // quad_perm xor2
    return v;
}
__device__ __forceinline__ float waveAllSum(float v) {
    v += __shfl_xor(v, 32); v += __shfl_xor(v, 16); v += __shfl_xor(v, 8);
    v += __shfl_xor(v, 4);  v += __shfl_xor(v, 2);  v += __shfl_xor(v, 1);
    return v;
}

// ---------------------------------------------------------------------------
// kA: 641 blocks.
//  [0,512): per-d sums of w1/b1 -> S1,S2,S11,S0b,Sb2
//  [512,576): partial column sums of g3/be3 -> Gp,Bp (plain stores)
//  [576,640): LN0 per batch -> xn, Xs
//  [640]: zero padded st2 accumulator
// ---------------------------------------------------------------------------
__global__ void __launch_bounds__(256) kA(
    const float* __restrict__ w1, const float* __restrict__ b1,
    const float* __restrict__ g3, const float* __restrict__ be3,
    const float* __restrict__ x, const float* __restrict__ g0,
    const float* __restrict__ be0,
    float* __restrict__ S1, float* __restrict__ S2, float* __restrict__ S11,
    float* __restrict__ S0b, float* __restrict__ Sb2,
    float* __restrict__ Gp, float* __restrict__ Bp,
    float* __restrict__ xn, float* __restrict__ Xs, float* __restrict__ st2) {
    int bid = blockIdx.x, tid = threadIdx.x;
    int wave = tid >> 6, lane = tid & 63;
    __shared__ float red[4][5];
    __shared__ float bc[2];
    if (bid < 512) {
        const float4* wr = (const float4*)(w1 + bid * 1024);
        const float4* br = (const float4*)(b1 + bid * 1024);
        float4 w = wr[tid], b = br[tid];
        float s1  = w.x + w.y + w.z + w.w;
        float s2  = w.x * w.x + w.y * w.y + w.z * w.z + w.w * w.w;
        float s11 = w.x * b.x + w.y * b.y + w.z * b.z + w.w * b.w;
        float s0  = b.x + b.y + b.z + b.w;
        float sb2 = b.x * b.x + b.y * b.y + b.z * b.z + b.w * b.w;
        s1 = waveAllSum(s1); s2 = waveAllSum(s2); s11 = waveAllSum(s11);
        s0 = waveAllSum(s0); sb2 = waveAllSum(sb2);
        if (lane == 0) {
            red[wave][0] = s1; red[wave][1] = s2; red[wave][2] = s11;
            red[wave][3] = s0; red[wave][4] = sb2;
        }
        __syncthreads();
        if (tid == 0) {
            float a0 = 0, a1 = 0, a2 = 0, a3 = 0, a4 = 0;
            for (int w4 = 0; w4 < 4; ++w4) {
                a0 += red[w4][0]; a1 += red[w4][1]; a2 += red[w4][2];
                a3 += red[w4][3]; a4 += red[w4][4];
            }
            S1[bid] = a0; S2[bid] = a1; S11[bid] = a2;
            S0b[bid] = a3; Sb2[bid] = a4;
        }
    } else if (bid < 576) {
        int jj = bid - 512;
        float ag0 = 0, ag1 = 0, ab0 = 0, ab1 = 0;
#pragma unroll
        for (int r = 0; r < 8; ++r) {
            const float* gr = g3 + (jj * 8 + r) * 512;
            const float* br = be3 + (jj * 8 + r) * 512;
            ag0 += gr[tid]; ag1 += gr[tid + 256];
            ab0 += br[tid]; ab1 += br[tid + 256];
        }
        Gp[jj * 512 + tid] = ag0; Gp[jj * 512 + tid + 256] = ag1;
        Bp[jj * 512 + tid] = ab0; Bp[jj * 512 + tid + 256] = ab1;
    } else if (bid < 640) {
        int b = bid - 576;
        float2 xv = ((const float2*)(x + b * 512))[tid];
        float sx = xv.x + xv.y, sxx = xv.x * xv.x + xv.y * xv.y;
        sx = waveAllSum(sx); sxx = waveAllSum(sxx);
        if (lane == 0) { red[wave][0] = sx; red[wave][1] = sxx; }
        __syncthreads();
        if (tid == 0) {
            float s = red[0][0] + red[1][0] + red[2][0] + red[3][0];
            float c = red[0][1] + red[1][1] + red[2][1] + red[3][1];
            float m = s * (1.f / 512.f);
            float var = c * (1.f / 512.f) - m * m;
            bc[0] = m; bc[1] = rsqrtf(var + EPS);
        }
        __syncthreads();
        float m = bc[0], rsd = bc[1];
        float2 g = ((const float2*)g0)[tid], be = ((const float2*)be0)[tid];
        float xn0 = (xv.x - m) * rsd * g.x + be.x;
        float xn1 = (xv.y - m) * rsd * g.y + be.y;
        ((float2*)(xn + b * 512))[tid] = make_float2(xn0, xn1);
        float sxn = waveAllSum(xn0 + xn1);
        __syncthreads();
        if (lane == 0) red[wave][0] = sxn;
        __syncthreads();
        if (tid == 0) Xs[b] = red[0][0] + red[1][0] + red[2][0] + red[3][0];
    } else {
        for (int t = tid; t < 2048; t += 256) st2[t] = 0.f;
    }
}

// ---------------------------------------------------------------------------
// kS: 66 blocks. [0,64): analytic LN1 stats per batch. [64]: fold Gp->G3s.
// [65]: fold Bp->Be3s.
// ---------------------------------------------------------------------------
__global__ void __launch_bounds__(256) kS(
    const float* __restrict__ xn,
    const float* __restrict__ S1, const float* __restrict__ S2,
    const float* __restrict__ S11, const float* __restrict__ S0b,
    const float* __restrict__ Sb2,
    const float* __restrict__ Gp, const float* __restrict__ Bp,
    float* __restrict__ rs1a, float* __restrict__ mm1a,
    float* __restrict__ G3s, float* __restrict__ Be3s) {
    int bid = blockIdx.x, tid = threadIdx.x;
    if (bid < 64) {
        int b = bid;
        __shared__ float red[4][2];
        float2 xv  = ((const float2*)(xn + b * 512))[tid];
        float2 s1  = ((const float2*)S1)[tid],  s0b = ((const float2*)S0b)[tid];
        float2 s2  = ((const float2*)S2)[tid],  s11 = ((const float2*)S11)[tid];
        float2 sb2 = ((const float2*)Sb2)[tid];
        float pm = fmaf(xv.x, s1.x, s0b.x) + fmaf(xv.y, s1.y, s0b.y);
        float pe = xv.x * xv.x * s2.x + 2.f * xv.x * s11.x + sb2.x
                 + xv.y * xv.y * s2.y + 2.f * xv.y * s11.y + sb2.y;
        pm = waveAllSum(pm); pe = waveAllSum(pe);
        int wave = tid >> 6, lane = tid & 63;
        if (lane == 0) { red[wave][0] = pm; red[wave][1] = pe; }
        __syncthreads();
        if (tid == 0) {
            float s = red[0][0] + red[1][0] + red[2][0] + red[3][0];
            float c = red[0][1] + red[1][1] + red[2][1] + red[3][1];
            float m1 = s * INV_N1, e1 = c * INV_N1;
            float r = rsqrtf(e1 - m1 * m1 + EPS);
            rs1a[b] = r; mm1a[b] = m1 * r;
        }
    } else if (bid == 64) {
        for (int u = tid; u < 512; u += 256) {
            float s = 0;
#pragma unroll 8
            for (int jj = 0; jj < 64; ++jj) s += Gp[jj * 512 + u];
            G3s[u] = s;
        }
    } else {
        for (int u = tid; u < 512; u += 256) {
            float s = 0;
#pragma unroll 8
            for (int jj = 0; jj < 64; ++jj) s += Bp[jj * 512 + u];
            Be3s[u] = s;
        }
    }
}

// ---------------------------------------------------------------------------
// k1: LN2 stat partials. 1024 blocks; DPP wave sums; per-block fold; 128
// cache-line-padded f32 atomics into st2.
// ---------------------------------------------------------------------------
__global__ void __launch_bounds__(256) k1(
    const float* __restrict__ w1, const float* __restrict__ b1,
    const float* __restrict__ g1, const float* __restrict__ be1,
    const float* __restrict__ w21, const float* __restrict__ w22,
    const float* __restrict__ b21, const float* __restrict__ b22,
    const float* __restrict__ xnp, const float* __restrict__ rs1a,
    const float* __restrict__ mm1a, float* __restrict__ st2) {
    int bid = blockIdx.x, tid = threadIdx.x;
    int d = bid >> 1;
    int u = ((bid & 1) << 8) + tid;
    int i = d * 512 + u;
    float2 W1 = ((const float2*)w1)[i], B1 = ((const float2*)b1)[i];
    float2 G1 = ((const float2*)g1)[i], E1 = ((const float2*)be1)[i];
    float2 A = ((const float2*)w21)[i], C = ((const float2*)w22)[i];
    float Ba = b21[i], Bc = b22[i];
    __shared__ float xcol[64], scA[64], scB[64];
    __shared__ float red[64][4][2];
    if (tid < 64) {
        xcol[tid] = xnp[tid * 512 + d];
        scA[tid] = rs1a[tid];
        scB[tid] = mm1a[tid];
    }
    __syncthreads();
    int wave = tid >> 6, lane = tid & 63;
    for (int b = 0; b < 64; ++b) {
        float rs1 = scA[b], mm1 = scB[b], xd = xcol[b];
        float t0 = fmaf(xd, W1.x, B1.x), t1 = fmaf(xd, W1.y, B1.y);
        float z0 = fmaf(t0, rs1, -mm1), z1 = fmaf(t1, rs1, -mm1);
        float y0 = fmaf(z0, G1.x, E1.x), y1 = fmaf(z1, G1.y, E1.y);
        float l0 = lrelu(y0), l1 = lrelu(y1);
        float c0 = fmaf(l0, A.x, fmaf(l1, A.y, Ba));
        float c1 = fmaf(l0, C.x, fmaf(l1, C.y, Bc));
        float v1 = c0 + c1;
        float v2 = fmaf(c0, c0, c1 * c1);
        v1 = waveSumDpp(v1);
        v2 = waveSumDpp(v2);
        if (lane == 63) { red[b][wave][0] = v1; red[b][wave][1] = v2; }
    }
    __syncthreads();
    if (tid < 128) {   // tid = b*2+k -> st2[tid*16] (64 B stride)
        int b = tid >> 1, k = tid & 1;
        float s = red[b][0][k] + red[b][1][k] + red[b][2][k] + red[b][3][k];
        unsafeAtomicAdd(&st2[tid * 16], s);
    }
}

// ---------------------------------------------------------------------------
// k2: main fused pass. 512 blocks (bu 32 x bd 16), 2 d's/thread, quad-DPP
// d-reduction, lane-private LDS accumulators (no in-loop barriers).
// LN2 stats finalized in prologue from st2. Plain partial stores.
// ---------------------------------------------------------------------------
struct Wt { float2 W1, B1, G1, E1, A, C, G2, E2, W3; float Ba, Bc, B3, G3v; };

__global__ void __launch_bounds__(256) k2(
    const float* __restrict__ w1, const float* __restrict__ b1,
    const float* __restrict__ g1, const float* __restrict__ be1,
    const float* __restrict__ w21, const float* __restrict__ w22,
    const float* __restrict__ b21, const float* __restrict__ b22,
    const float* __restrict__ g2, const float* __restrict__ be2,
    const float* __restrict__ w3, const float* __restrict__ b3,
    const float* __restrict__ g3,
    const float* __restrict__ xnp, const float* __restrict__ rs1a,
    const float* __restrict__ mm1a, const float* __restrict__ st2,
    float* __restrict__ pp, float* __restrict__ qp) {
    int bu = blockIdx.x & 31, bd = blockIdx.x >> 5, tid = threadIdx.x;
    int lane = tid & 63, wave = tid >> 6;
    int ul = (lane >> 2) & 15, d0 = lane & 3;
    int u = bu * 16 + ul;
    int dl0 = wave * 8 + d0 * 2;
    Wt wt[2];
#pragma unroll
    for (int j = 0; j < 2; ++j) {
        int d = bd * 32 + dl0 + j;
        int i = d * 512 + u;
        wt[j].W1 = ((const float2*)w1)[i];  wt[j].B1 = ((const float2*)b1)[i];
        wt[j].G1 = ((const float2*)g1)[i];  wt[j].E1 = ((const float2*)be1)[i];
        wt[j].A  = ((const float2*)w21)[i]; wt[j].C  = ((const float2*)w22)[i];
        wt[j].G2 = ((const float2*)g2)[i];  wt[j].E2 = ((const float2*)be2)[i];
        wt[j].W3 = ((const float2*)w3)[i];
        wt[j].Ba = b21[i]; wt[j].Bc = b22[i]; wt[j].B3 = b3[i]; wt[j].G3v = g3[i];
    }
    __shared__ float4 sc[64];
    __shared__ float sxn[64][32];
    __shared__ float comb[4][64][16][3];   // [wave][b][u][stat] 48 KB
    {
        float* cz = &comb[0][0][0][0];
        for (int t = tid; t < 4 * 64 * 16 * 3; t += 256) cz[t] = 0.f;
    }
    if (tid < 64) {
        float ssum = st2[(tid * 2) * 16], s2sum = st2[(tid * 2 + 1) * 16];
        float mm = ssum * INV_N1;
        float var = s2sum * INV_N1 - mm * mm;
        float r2 = rsqrtf(var + EPS);
        sc[tid] = make_float4(rs1a[tid], mm1a[tid], r2, mm * r2);
    }
    for (int idx = tid; idx < 2048; idx += 256)
        sxn[idx >> 5][idx & 31] = xnp[(idx >> 5) * 512 + bd * 32 + (idx & 31)];
    __syncthreads();
    for (int b = 0; b < 64; ++b) {
        float4 s4 = sc[b];   // rs1, m1*rs1, rs2, m2*rs2
        float p = 0, q = 0, q2 = 0;
#pragma unroll
        for (int j = 0; j < 2; ++j) {
            float xd = sxn[b][dl0 + j];
            float t0 = fmaf(xd, wt[j].W1.x, wt[j].B1.x), t1 = fmaf(xd, wt[j].W1.y, wt[j].B1.y);
            float z0 = fmaf(t0, s4.x, -s4.y), z1 = fmaf(t1, s4.x, -s4.y);
            float y0 = fmaf(z0, wt[j].G1.x, wt[j].E1.x), y1 = fmaf(z1, wt[j].G1.y, wt[j].E1.y);
            float l0 = lrelu(y0), l1 = lrelu(y1);
            float c0 = fmaf(l0, wt[j].A.x, fmaf(l1, wt[j].A.y, wt[j].Ba));
            float c1 = fmaf(l0, wt[j].C.x, fmaf(l1, wt[j].C.y, wt[j].Bc));
            float z20 = fmaf(c0, s4.z, -s4.w), z21 = fmaf(c1, s4.z, -s4.w);
            float y20 = fmaf(z20, wt[j].G2.x, wt[j].E2.x), y21 = fmaf(z21, wt[j].G2.y, wt[j].E2.y);
            float m0 = lrelu(y20), m1v = lrelu(y21);
            float l3 = fmaf(m0, wt[j].W3.x, fmaf(m1v, wt[j].W3.y, wt[j].B3));
            p = fmaf(l3, wt[j].G3v, p); q += l3; q2 = fmaf(l3, l3, q2);
        }
        p = quadSum(p); q = quadSum(q); q2 = quadSum(q2);
        if (d0 < 3) {
            float v = (d0 == 0) ? p : ((d0 == 1) ? q : q2);
            comb[wave][b][ul][d0] += v;   // lane-private slot
        }
    }
    __syncthreads();
    // fold p over waves -> per-(b,u) partial for this bd
#pragma unroll
    for (int r = 0; r < 4; ++r) {
        int idx = r * 256 + tid;
        int b = idx >> 4, uu = idx & 15;
        float s = comb[0][b][uu][0] + comb[1][b][uu][0]
                + comb[2][b][uu][0] + comb[3][b][uu][0];
        pp[(bd * 64 + b) * 512 + bu * 16 + uu] = s;
    }
    // fold q,q2 over waves AND u -> per-(block,b) scalars
    if (tid < 128) {
        int b = tid >> 1, st = 1 + (tid & 1);
        float s = 0;
#pragma unroll
        for (int w = 0; w < 4; ++w)
#pragma unroll
            for (int uu = 0; uu < 16; ++uu) s += comb[w][b][uu][st];
        qp[(bd * 32 + bu) * 128 + b * 2 + (st - 1)] = s;
    }
}

// ---------------------------------------------------------------------------
// k3: LN3 stats from q-partials, fold p-partials, finalize output.
// ---------------------------------------------------------------------------
__global__ void __launch_bounds__(512) k3(
    const float* __restrict__ pp, const float* __restrict__ qp,
    const float* __restrict__ G3s, const float* __restrict__ Be3s,
    const float* __restrict__ Xs, const float* __restrict__ bias,
    float* __restrict__ out) {
    int b = blockIdx.x, u = threadIdx.x;
    float q  = qp[u * 128 + b * 2 + 0];
    float q2 = qp[u * 128 + b * 2 + 1];
    __shared__ float red[8][2];
    __shared__ float bc2[2];
    float sq = waveAllSum(q), sq2 = waveAllSum(q2);
    int wave = u >> 6, lane = u & 63;
    if (lane == 0) { red[wave][0] = sq; red[wave][1] = sq2; }
    __syncthreads();
    if (u == 0) {
        float a = 0, c = 0;
        for (int w = 0; w < 8; ++w) { a += red[w][0]; c += red[w][1]; }
        float m3 = a * INV_N3;
        float e3 = c * INV_N3;
        bc2[0] = m3; bc2[1] = rsqrtf(e3 - m3 * m3 + EPS);
    }
    __syncthreads();
    float p = 0;
#pragma unroll 4
    for (int bd = 0; bd < 16; ++bd) p += pp[(bd * 64 + b) * 512 + u];
    float m3 = bc2[0], rs3 = bc2[1];
    float val = rs3 * (p - m3 * G3s[u]) + Be3s[u] + Xs[b] + bias[u];
    out[b * 512 + u] = lrelu(val);
}

extern "C" void kernel_launch(void* const* d_in, const int* in_sizes, int n_in,
                              void* d_out, int out_size, void* d_ws, size_t ws_size,
                              hipStream_t stream) {
    const float* x   = (const float*)d_in[0];
    const float* w1  = (const float*)d_in[1];
    const float* b1  = (const float*)d_in[2];
    const float* w21 = (const float*)d_in[3];
    const float* w22 = (const float*)d_in[4];
    const float* b21 = (const float*)d_in[5];
    const float* b22 = (const float*)d_in[6];
    const float* w3  = (const float*)d_in[7];
    const float* b3  = (const float*)d_in[8];
    const float* bias= (const float*)d_in[9];
    const float* g0  = (const float*)d_in[10];
    const float* be0 = (const float*)d_in[11];
    const float* g1  = (const float*)d_in[12];
    const float* be1 = (const float*)d_in[13];
    const float* g2  = (const float*)d_in[14];
    const float* be2 = (const float*)d_in[15];
    const float* g3  = (const float*)d_in[16];
    const float* be3 = (const float*)d_in[17];
    float* out = (float*)d_out;
    char* ws = (char*)d_ws;

    float* xn   = (float*)(ws);             // 131072 [B][D]
    float* S1   = (float*)(ws + 131072);
    float* S2   = (float*)(ws + 133120);
    float* S11  = (float*)(ws + 135168);
    float* S0b  = (float*)(ws + 137216);
    float* Sb2  = (float*)(ws + 139264);
    float* rs1a = (float*)(ws + 141312);
    float* mm1a = (float*)(ws + 141568);
    float* Xs   = (float*)(ws + 141824);
    float* st2  = (float*)(ws + 142080);    // 8192 B padded accumulator
    float* G3s  = (float*)(ws + 150272);
    float* Be3s = (float*)(ws + 152320);
    float* Gp   = (float*)(ws + 154368);    // 131072 [64][512]
    float* Bp   = (float*)(ws + 285440);    // 131072
    float* qp   = (float*)(ws + 416512);    // 262144 [512][128]
    float* pp   = (float*)(ws + 678656);    // 2097152 [16][64][512]

    hipLaunchKernelGGL(kA, dim3(641), dim3(256), 0, stream,
                       w1, b1, g3, be3, x, g0, be0,
                       S1, S2, S11, S0b, Sb2, Gp, Bp, xn, Xs, st2);
    hipLaunchKernelGGL(kS, dim3(66), dim3(256), 0, stream,
                       xn, S1, S2, S11, S0b, Sb2, Gp, Bp,
                       rs1a, mm1a, G3s, Be3s);
    hipLaunchKernelGGL(k1, dim3(1024), dim3(256), 0, stream,
                       w1, b1, g1, be1, w21, w22, b21, b22, xn, rs1a, mm1a, st2);
    hipLaunchKernelGGL(k2, dim3(512), dim3(256), 0, stream,
                       w1, b1, g1, be1, w21, w22, b21, b22, g2, be2, w3, b3, g3,
                       xn, rs1a, mm1a, st2, pp, qp);
    hipLaunchKernelGGL(k3, dim3(64), dim3(512), 0, stream,
                       pp, qp, G3s, Be3s, Xs, bias, out);
}